// Round 22
// baseline (118.374 us; speedup 1.0000x reference)
//
#include <hip/hip_runtime.h>
#include <hip/hip_bf16.h>

#define NQ       131072     // 32*4096 queries
#define KC       1024       // codes
#define DIM      64
#define MARGIN_A 7.5e-5f    // acc-space: 1.2e-5 f32/split err + 2x1.5e-5 trunc + slack
#define RGRID    2048       // rescue grid (blocks)

typedef __attribute__((ext_vector_type(8))) short  s8bf;   // 8 bf16 (4 VGPRs)
typedef __attribute__((ext_vector_type(4))) float  f32x4;  // MFMA acc

union BF8 { s8bf v; unsigned short u[8]; };

__device__ __forceinline__ unsigned short f2bf_u(float f) {
    union { __hip_bfloat16 h; unsigned short u; } cv;
    cv.h = __float2bfloat16(f);
    return cv.u;
}
__device__ __forceinline__ float bfu2f(unsigned short u) {
    union { __hip_bfloat16 h; unsigned short u; } cv;
    cv.u = u;
    return __bfloat162float(cv.h);
}

// ---------- K0: prep, PARALLEL (1 wave/code): 16x16 B-frags + f64 codebook + zero accs ----------
__global__ __launch_bounds__(64) void k_prep(const float* __restrict__ emb,
                                             unsigned short* __restrict__ wB,
                                             double* __restrict__ eT,     // [64][1024] f64
                                             double* __restrict__ wB2D,
                                             int* __restrict__ counts,
                                             int* __restrict__ nflag,
                                             float* __restrict__ lossp) {
    const int c = blockIdx.x;                  // code (1024 blocks)
    const int i = threadIdx.x;                 // dim  (64 lanes)
    if (i == 0) counts[c] = 0;
    if (c == 0 && i == 0) { *nflag = 0; *lossp = 0.f; }

    float e = emb[(size_t)c * DIM + i];
    float sq = e * e;
    #pragma unroll
    for (int off = 1; off < 64; off <<= 1) sq += __shfl_xor(sq, off);
    float inv = 1.0f / fmaxf(sqrtf(sq), 1e-12f);
    float h = e * inv;
    unsigned short hi = f2bf_u(h);
    unsigned short lo = f2bf_u(h - bfu2f(hi));
    const int t = c >> 4, col = c & 15;
    const int s_ = i >> 5, g = (i >> 3) & 3, j = i & 7;
    const int ln = col + 16 * g;
    wB[((t*4 + s_*2 + 0) * 64 + ln) * 8 + j] = hi;
    wB[((t*4 + s_*2 + 1) * 64 + ln) * 8 + j] = lo;

    double ed = (double)e;
    double sd = ed * ed;
    #pragma unroll
    for (int off = 1; off < 64; off <<= 1) sd += __shfl_xor(sd, off);
    double dnd = fmax(sqrt(sd), 1e-12);
    double eh  = ed / dnd;
    eT[(size_t)i * KC + c] = eh;
    double b2 = eh * eh;
    #pragma unroll
    for (int off = 1; off < 64; off <<= 1) b2 += __shfl_xor(b2, off);
    if (i == 0) wB2D[c] = b2;
}

// ---------- K1: MFMA distances; 64 q/wave, barrier-free, DUAL 3-DEEP CHAINS per tile ----------
// a = (1.5 + 3 MFMAs) + (0 + 3 MFMAs): 8 independent chains/wave, reassoc err ~2e-7.
__global__ __launch_bounds__(256) void k_assign(const float* __restrict__ inp,
                                                const unsigned short* __restrict__ wB,
                                                float* __restrict__ idx_out,
                                                int* __restrict__ flag_list,
                                                int* __restrict__ nflag) {
    const int tid  = threadIdx.x;
    const int lane = tid & 63, wv = tid >> 6;
    const int col  = lane & 15, g  = lane >> 4;
    const int qbase = blockIdx.x * 256 + wv * 64;      // 64 queries per wave

    // A-frags for 4 row-groups of 16 queries (r5-proven layout, negated)
    BF8 ah[4][2], al[4][2];
    #pragma unroll
    for (int s = 0; s < 4; ++s) {
        const float4* q4 = reinterpret_cast<const float4*>(inp + (size_t)(qbase + 16*s + col) * DIM);
        float4 xa = q4[2*g], xb = q4[2*g + 1], ya = q4[8 + 2*g], yb = q4[9 + 2*g];
        float x[16] = { xa.x, xa.y, xa.z, xa.w, xb.x, xb.y, xb.z, xb.w,
                        ya.x, ya.y, ya.z, ya.w, yb.x, yb.y, yb.z, yb.w };
        float sq = 0.f;
        #pragma unroll
        for (int i = 0; i < 16; ++i) sq += x[i] * x[i];
        sq += __shfl_xor(sq, 16);
        sq += __shfl_xor(sq, 32);
        float ninv = -1.0f / fmaxf(sqrtf(sq), 1e-12f);   // NEGATED normalize
        #pragma unroll
        for (int i = 0; i < 8; ++i) {
            float h0 = x[i] * ninv, h1 = x[8 + i] * ninv; // -x_hat
            unsigned short hi0 = f2bf_u(h0);
            unsigned short hi1 = f2bf_u(h1);
            ah[s][0].u[i] = hi0;  al[s][0].u[i] = f2bf_u(h0 - bfu2f(hi0));
            ah[s][1].u[i] = hi1;  al[s][1].u[i] = f2bf_u(h1 - bfu2f(hi1));
        }
    }

    int best[4][4], best2[4][4];
    #pragma unroll
    for (int s = 0; s < 4; ++s)
        #pragma unroll
        for (int r = 0; r < 4; ++r) { best[s][r] = 0x7FFFFFFF; best2[s][r] = 0x7FFFFFFF; }

    // Barrier-free tile stream: 64 tiles x 4 frags, 1-tile software prefetch.
    const s8bf* wBs = reinterpret_cast<const s8bf*>(wB);
    s8bf nb0 = wBs[0*64 + lane];
    s8bf nb1 = wBs[1*64 + lane];
    s8bf nb2 = wBs[2*64 + lane];
    s8bf nb3 = wBs[3*64 + lane];

    for (int gt = 0; gt < 64; ++gt) {          // 64 tiles of 16 codes
        s8bf bh0 = nb0, bl0 = nb1, bh1 = nb2, bl1 = nb3;
        if (gt < 63) {                         // prefetch next tile
            const s8bf* p = wBs + (gt + 1) * 4 * 64 + lane;
            nb0 = p[0]; nb1 = p[64]; nb2 = p[128]; nb3 = p[192];
        }
        #pragma unroll
        for (int s = 0; s < 4; ++s) {          // 4 row-groups; 2 chains each
            f32x4 aA = {1.5f, 1.5f, 1.5f, 1.5f};        // chain A: 3 deep
            f32x4 aB = {0.f, 0.f, 0.f, 0.f};            // chain B: 3 deep
            aA = __builtin_amdgcn_mfma_f32_16x16x32_bf16(ah[s][0].v, bh0, aA, 0, 0, 0);
            aB = __builtin_amdgcn_mfma_f32_16x16x32_bf16(ah[s][1].v, bh1, aB, 0, 0, 0);
            aA = __builtin_amdgcn_mfma_f32_16x16x32_bf16(ah[s][0].v, bl0, aA, 0, 0, 0);
            aB = __builtin_amdgcn_mfma_f32_16x16x32_bf16(ah[s][1].v, bl1, aB, 0, 0, 0);
            aA = __builtin_amdgcn_mfma_f32_16x16x32_bf16(al[s][0].v, bh0, aA, 0, 0, 0);
            aB = __builtin_amdgcn_mfma_f32_16x16x32_bf16(al[s][1].v, bh1, aB, 0, 0, 0);
            #pragma unroll
            for (int r = 0; r < 4; ++r) {
                float a = aA[r] + aB[r];       // reassoc delta ~2e-7 << margin
                int p = (__float_as_int(a) & 0xFFFFFFC0) | gt;
                int bo = best[s][r];
                int b2n;
                asm("v_med3_i32 %0, %1, %2, %3"
                    : "=v"(b2n) : "v"(bo), "v"(best2[s][r]), "v"(p));
                best2[s][r] = b2n;             // median(best, best2, p)
                best[s][r]  = min(bo, p);
            }
        }
    }

    // 16-lane argmin reduce; col carried separately, selected by packed compare
    int colb[4][4];
    #pragma unroll
    for (int s = 0; s < 4; ++s)
        #pragma unroll
        for (int r = 0; r < 4; ++r) colb[s][r] = col;

    #pragma unroll
    for (int s = 0; s < 4; ++s) {
        #pragma unroll
        for (int off = 1; off < 16; off <<= 1) {
            #pragma unroll
            for (int r = 0; r < 4; ++r) {
                int ob  = __shfl_xor(best[s][r],  off);
                int ob2 = __shfl_xor(best2[s][r], off);
                int oc  = __shfl_xor(colb[s][r],  off);
                int bo  = best[s][r];
                colb[s][r]  = (ob < bo) ? oc : colb[s][r];  // ties keep self (flagged anyway)
                best[s][r]  = min(bo, ob);
                best2[s][r] = min(min(best2[s][r], ob2), max(bo, ob));
            }
        }
        #pragma unroll
        for (int r = 0; r < 4; ++r) {
            if (col == r) {                    // owner lane for this query row
                int   q  = qbase + 16*s + 4*g + r;
                int   pk = best[s][r];
                float a1 = __int_as_float(pk & 0xFFFFFFC0);          // acc-space
                float a2 = __int_as_float(best2[s][r] & 0xFFFFFFC0);
                int code = ((pk & 63) << 4) | colb[s][r];            // gt*16 + col
                idx_out[q] = (float)code;
                if (a2 - a1 < MARGIN_A) {      // ambiguous -> f64 rescue
                    int slot = atomicAdd(nflag, 1);
                    flag_list[slot] = q;
                }
            }
        }
    }
}

// ---------- K2: f64 rescore, coalesced eT + 4 independent dot chains (proven) ----------
__global__ __launch_bounds__(256) void k_rescue(const float* __restrict__ inp,
                                                const double* __restrict__ eT,
                                                const double* __restrict__ wB2D,
                                                const int* __restrict__ flag_list,
                                                const int* __restrict__ nflag,
                                                float* __restrict__ idx_out) {
    __shared__ double xh[DIM];
    __shared__ double Ash;
    __shared__ double sdw[4];
    __shared__ int    siw[4];
    const int tid = threadIdx.x;
    const int lane = tid & 63, wv = tid >> 6;
    const int n = *nflag;

    for (int j = blockIdx.x; j < n; j += gridDim.x) {   // uniform trip per block
        const int q = flag_list[j];
        if (tid < 64) {
            double xv = (double)inp[(size_t)q * DIM + tid];
            double s = xv * xv;
            #pragma unroll
            for (int off = 32; off; off >>= 1) s += __shfl_xor(s, off);
            double dn = fmax(sqrt(s), 1e-12);
            double h  = xv / dn;
            xh[tid] = h;
            double a = h * h;
            #pragma unroll
            for (int off = 32; off; off >>= 1) a += __shfl_xor(a, off);
            if (tid == 0) Ash = a;
        }
        __syncthreads();
        const double A = Ash;

        double dot0 = 0.0, dot1 = 0.0, dot2 = 0.0, dot3 = 0.0;
        #pragma unroll 8
        for (int i = 0; i < DIM; ++i) {
            double xi = xh[i];                           // LDS broadcast
            const double* row = eT + (size_t)i * KC + tid;
            dot0 += xi * row[0];
            dot1 += xi * row[256];
            dot2 += xi * row[512];
            dot3 += xi * row[768];
        }
        double bd = 1e300; int bi = 1 << 30;
        double d0 = (A + wB2D[tid      ]) - 2.0 * dot0;
        double d1 = (A + wB2D[tid + 256]) - 2.0 * dot1;
        double d2 = (A + wB2D[tid + 512]) - 2.0 * dot2;
        double d3 = (A + wB2D[tid + 768]) - 2.0 * dot3;
        if (d0 < bd) { bd = d0; bi = tid;       }        // ascending c: first-min
        if (d1 < bd) { bd = d1; bi = tid + 256; }
        if (d2 < bd) { bd = d2; bi = tid + 512; }
        if (d3 < bd) { bd = d3; bi = tid + 768; }
        #pragma unroll
        for (int off = 1; off < 64; off <<= 1) {         // 64-lane (d,i) min-reduce
            double od = __shfl_xor(bd, off);
            int    oi = __shfl_xor(bi, off);
            if (od < bd || (od == bd && oi < bi)) { bd = od; bi = oi; }
        }
        if (lane == 0) { sdw[wv] = bd; siw[wv] = bi; }
        __syncthreads();
        if (tid == 0) {
            double B = sdw[0]; int I = siw[0];
            #pragma unroll
            for (int i = 1; i < 4; ++i)
                if (sdw[i] < B || (sdw[i] == B && siw[i] < I)) { B = sdw[i]; I = siw[i]; }
            idx_out[q] = (float)I;                       // final
        }
        __syncthreads();
    }
}

// ---------- K3: gather + loss + hist, EXPLICIT 4-WAY ILP (r19-proven) ----------
__global__ __launch_bounds__(256) void k_gather_loss(const float* __restrict__ inp,
                                                     const float* __restrict__ emb,
                                                     const float* __restrict__ idx_out,
                                                     float* __restrict__ qout,
                                                     float* __restrict__ loss,
                                                     int* __restrict__ counts) {
    __shared__ int h[KC];
    const int tid = threadIdx.x;
    for (int i = tid; i < KC; i += 256) h[i] = 0;
    __syncthreads();

    const int gid = blockIdx.x * 256 + tid;            // 524288 threads x 4 e4 each

    int kk[4];
    #pragma unroll
    for (int it = 0; it < 4; ++it)
        kk[it] = ((int)idx_out[(gid + it * 524288) >> 4]) & (KC - 1);

    float4 qv[4], fv[4];
    #pragma unroll
    for (int it = 0; it < 4; ++it) {
        int e4 = gid + it * 524288;
        qv[it] = reinterpret_cast<const float4*>(emb + (size_t)kk[it] * DIM)[e4 & 15];
        fv[it] = reinterpret_cast<const float4*>(inp)[e4];
    }

    float lsum = 0.f;
    #pragma unroll
    for (int it = 0; it < 4; ++it) {
        int e4 = gid + it * 524288;
        float ux = qv[it].x - fv[it].x, uy = qv[it].y - fv[it].y;
        float uz = qv[it].z - fv[it].z, uw = qv[it].w - fv[it].w;
        lsum += ux*ux + uy*uy + uz*uz + uw*uw;
        reinterpret_cast<float4*>(qout)[e4] = qv[it];
        if ((e4 & 15) == 0) atomicAdd(&h[kk[it]], 1);  // count each query once
    }
    __syncthreads();                                   // hist adds done
    for (int i = tid; i < KC; i += 256) {
        int v = h[i];
        if (v) atomicAdd(&counts[i], v);
    }
    #pragma unroll
    for (int off = 32; off; off >>= 1) lsum += __shfl_xor(lsum, off);
    __shared__ float wsum[4];
    int wid = tid >> 6, lane = tid & 63;
    if (lane == 0) wsum[wid] = lsum;
    __syncthreads();
    if (tid == 0)
        atomicAdd(loss, (wsum[0] + wsum[1]) + (wsum[2] + wsum[3]));
}

// ---------- K4: perplexity / usage / vq_loss ----------
__global__ __launch_bounds__(1024) void k_stats2(const int* __restrict__ counts,
                                                 float* __restrict__ out3) {
    int t = threadIdx.x;
    int c = counts[t];
    float p    = (float)c * (1.0f / (float)NQ);
    float ent  = p * logf(p + 1e-10f);
    float used = (c > 0) ? 1.0f : 0.0f;
    #pragma unroll
    for (int off = 32; off; off >>= 1) {
        ent  += __shfl_xor(ent, off);
        used += __shfl_xor(used, off);
    }
    __shared__ float se[16], su[16];
    int w = t >> 6, l = t & 63;
    if (l == 0) { se[w] = ent; su[w] = used; }
    __syncthreads();
    if (t == 0) {
        float E = 0.f, U = 0.f;
        #pragma unroll
        for (int i = 0; i < 16; ++i) { E += se[i]; U += su[i]; }
        float L = out3[0];                             // loss accumulated here
        out3[0] = L * 1.25f / 8388608.0f;              // vq_loss (q + 0.25*e)
        out3[1] = expf(-E);                            // perplexity
        out3[2] = U * (1.0f / 1024.0f);                // codebook_usage
    }
}

// ---------- launch (5 kernels) ----------
// d_out (f32, 8519683): [0,8388608) quantized | [8388608,8519680) idx | 3 scalars
// Scratch in the quantized region (consumed by k_rescue, overwritten by gather):
//   flag_list @ float 0 (<=512 KB) | eT f64[64][1024] @ float 1048576 (512 KB)
// d_ws: counts[1024]@0 | wB u16[131072]@4096 | wB2D f64[1024]@266240 | nflag@274432
extern "C" void kernel_launch(void* const* d_in, const int* in_sizes, int n_in,
                              void* d_out, int out_size, void* d_ws, size_t ws_size,
                              hipStream_t stream) {
    const float* inp = (const float*)d_in[0];   // [32,4096,64] f32
    const float* emb = (const float*)d_in[1];   // [1024,64] f32

    float*  qout      = (float*)d_out;
    int*    flag_list = (int*)d_out;                        // quantized region, part 1
    double* eT        = (double*)((float*)d_out + 1048576); // quantized region, part 2
    float*  idx_out   = (float*)d_out + 8388608;
    float*  out3      = (float*)d_out + 8519680;

    int*            counts = (int*)d_ws;
    unsigned short* wB     = (unsigned short*)((char*)d_ws + 4096);
    double*         wB2D   = (double*)((char*)d_ws + 266240);
    int*            nflag  = (int*)((char*)d_ws + 274432);

    hipLaunchKernelGGL(k_prep,        dim3(1024), dim3(64),   0, stream,
                       emb, wB, eT, wB2D, counts, nflag, out3);
    hipLaunchKernelGGL(k_assign,      dim3(512),  dim3(256),  0, stream,
                       inp, wB, idx_out, flag_list, nflag);
    hipLaunchKernelGGL(k_rescue,      dim3(RGRID), dim3(256), 0, stream,
                       inp, eT, wB2D, flag_list, nflag, idx_out);
    hipLaunchKernelGGL(k_gather_loss, dim3(2048), dim3(256),  0, stream,
                       inp, emb, idx_out, qout, out3, counts);
    hipLaunchKernelGGL(k_stats2,      dim3(1),    dim3(1024), 0, stream, counts, out3);
}

// Round 23
// 112.467 us; speedup vs baseline: 1.0525x; 1.0525x over previous
//
#include <hip/hip_runtime.h>
#include <hip/hip_bf16.h>

#define NQ       131072     // 32*4096 queries
#define KC       1024       // codes
#define DIM      64
#define MARGIN_A 7.5e-5f    // acc-space: 1.2e-5 f32/split err + 2x1.5e-5 trunc + slack
#define RGRID    2048       // rescue grid (blocks)

typedef __attribute__((ext_vector_type(8))) short  s8bf;   // 8 bf16 (4 VGPRs)
typedef __attribute__((ext_vector_type(4))) float  f32x4;  // MFMA acc

union BF8 { s8bf v; unsigned short u[8]; };

__device__ __forceinline__ unsigned short f2bf_u(float f) {
    union { __hip_bfloat16 h; unsigned short u; } cv;
    cv.h = __float2bfloat16(f);
    return cv.u;
}
__device__ __forceinline__ float bfu2f(unsigned short u) {
    union { __hip_bfloat16 h; unsigned short u; } cv;
    cv.u = u;
    return __bfloat162float(cv.h);
}

// ---------- K0: prep, PARALLEL (1 wave/code): 16x16 B-frags + f64 codebook + zero accs ----------
// B-frag (16x16x32 layout, proven r5-r21): t=c>>4, col=c&15; for dim k: s_=k>>5,
// g=(k>>3)&3, j=k&7, ln=col+16g; u16 idx = ((t*4+s_*2+comp)*64+ln)*8+j.
__global__ __launch_bounds__(64) void k_prep(const float* __restrict__ emb,
                                             unsigned short* __restrict__ wB,
                                             double* __restrict__ eT,     // [64][1024] f64
                                             double* __restrict__ wB2D,
                                             int* __restrict__ counts,
                                             int* __restrict__ nflag,
                                             float* __restrict__ lossp) {
    const int c = blockIdx.x;                  // code (1024 blocks)
    const int i = threadIdx.x;                 // dim  (64 lanes)
    if (i == 0) counts[c] = 0;
    if (c == 0 && i == 0) { *nflag = 0; *lossp = 0.f; }

    float e = emb[(size_t)c * DIM + i];
    float sq = e * e;
    #pragma unroll
    for (int off = 1; off < 64; off <<= 1) sq += __shfl_xor(sq, off);
    float inv = 1.0f / fmaxf(sqrtf(sq), 1e-12f);
    float h = e * inv;
    unsigned short hi = f2bf_u(h);
    unsigned short lo = f2bf_u(h - bfu2f(hi));
    const int t = c >> 4, col = c & 15;
    const int s_ = i >> 5, g = (i >> 3) & 3, j = i & 7;
    const int ln = col + 16 * g;
    wB[((t*4 + s_*2 + 0) * 64 + ln) * 8 + j] = hi;
    wB[((t*4 + s_*2 + 1) * 64 + ln) * 8 + j] = lo;

    double ed = (double)e;
    double sd = ed * ed;
    #pragma unroll
    for (int off = 1; off < 64; off <<= 1) sd += __shfl_xor(sd, off);
    double dnd = fmax(sqrt(sd), 1e-12);
    double eh  = ed / dnd;
    eT[(size_t)i * KC + c] = eh;
    double b2 = eh * eh;
    #pragma unroll
    for (int off = 1; off < 64; off <<= 1) b2 += __shfl_xor(b2, off);
    if (i == 0) wB2D[c] = b2;
}

// ---------- K1: MFMA distances; 64 q/wave, BARRIER-FREE, direct L2->VGPR (best: 57.4us) ----------
// acc = 1.5 - dot in [0.49, 2.51]; d = 2*acc (monotone). No LDS, no barriers.
__global__ __launch_bounds__(256) void k_assign(const float* __restrict__ inp,
                                                const unsigned short* __restrict__ wB,
                                                float* __restrict__ idx_out,
                                                int* __restrict__ flag_list,
                                                int* __restrict__ nflag) {
    const int tid  = threadIdx.x;
    const int lane = tid & 63, wv = tid >> 6;
    const int col  = lane & 15, g  = lane >> 4;
    const int qbase = blockIdx.x * 256 + wv * 64;      // 64 queries per wave

    // A-frags for 4 row-groups of 16 queries (r5-proven layout, negated)
    BF8 ah[4][2], al[4][2];
    #pragma unroll
    for (int s = 0; s < 4; ++s) {
        const float4* q4 = reinterpret_cast<const float4*>(inp + (size_t)(qbase + 16*s + col) * DIM);
        float4 xa = q4[2*g], xb = q4[2*g + 1], ya = q4[8 + 2*g], yb = q4[9 + 2*g];
        float x[16] = { xa.x, xa.y, xa.z, xa.w, xb.x, xb.y, xb.z, xb.w,
                        ya.x, ya.y, ya.z, ya.w, yb.x, yb.y, yb.z, yb.w };
        float sq = 0.f;
        #pragma unroll
        for (int i = 0; i < 16; ++i) sq += x[i] * x[i];
        sq += __shfl_xor(sq, 16);
        sq += __shfl_xor(sq, 32);
        float ninv = -1.0f / fmaxf(sqrtf(sq), 1e-12f);   // NEGATED normalize
        #pragma unroll
        for (int i = 0; i < 8; ++i) {
            float h0 = x[i] * ninv, h1 = x[8 + i] * ninv; // -x_hat
            unsigned short hi0 = f2bf_u(h0);
            unsigned short hi1 = f2bf_u(h1);
            ah[s][0].u[i] = hi0;  al[s][0].u[i] = f2bf_u(h0 - bfu2f(hi0));
            ah[s][1].u[i] = hi1;  al[s][1].u[i] = f2bf_u(h1 - bfu2f(hi1));
        }
    }

    int best[4][4], best2[4][4];
    #pragma unroll
    for (int s = 0; s < 4; ++s)
        #pragma unroll
        for (int r = 0; r < 4; ++r) { best[s][r] = 0x7FFFFFFF; best2[s][r] = 0x7FFFFFFF; }

    // Barrier-free tile stream: 64 tiles x 4 frags, 1-tile software prefetch.
    const s8bf* wBs = reinterpret_cast<const s8bf*>(wB);
    s8bf nb0 = wBs[0*64 + lane];
    s8bf nb1 = wBs[1*64 + lane];
    s8bf nb2 = wBs[2*64 + lane];
    s8bf nb3 = wBs[3*64 + lane];

    for (int gt = 0; gt < 64; ++gt) {          // 64 tiles of 16 codes
        s8bf bh0 = nb0, bl0 = nb1, bh1 = nb2, bl1 = nb3;
        if (gt < 63) {                         // prefetch next tile
            const s8bf* p = wBs + (gt + 1) * 4 * 64 + lane;
            nb0 = p[0]; nb1 = p[64]; nb2 = p[128]; nb3 = p[192];
        }
        #pragma unroll
        for (int s = 0; s < 4; ++s) {          // 4 row-groups share the B regs
            f32x4 acc = {1.5f, 1.5f, 1.5f, 1.5f};    // acc = 1.5 - dot
            acc = __builtin_amdgcn_mfma_f32_16x16x32_bf16(ah[s][0].v, bh0, acc, 0, 0, 0);
            acc = __builtin_amdgcn_mfma_f32_16x16x32_bf16(ah[s][1].v, bh1, acc, 0, 0, 0);
            acc = __builtin_amdgcn_mfma_f32_16x16x32_bf16(ah[s][0].v, bl0, acc, 0, 0, 0);
            acc = __builtin_amdgcn_mfma_f32_16x16x32_bf16(ah[s][1].v, bl1, acc, 0, 0, 0);
            acc = __builtin_amdgcn_mfma_f32_16x16x32_bf16(al[s][0].v, bh0, acc, 0, 0, 0);
            acc = __builtin_amdgcn_mfma_f32_16x16x32_bf16(al[s][1].v, bh1, acc, 0, 0, 0);
            #pragma unroll
            for (int r = 0; r < 4; ++r) {
                // 3-op update: and_or pack | med3 best2 | min best
                int p = (__float_as_int(acc[r]) & 0xFFFFFFC0) | gt;
                int bo = best[s][r];
                int b2n;
                asm("v_med3_i32 %0, %1, %2, %3"
                    : "=v"(b2n) : "v"(bo), "v"(best2[s][r]), "v"(p));
                best2[s][r] = b2n;                    // median(best, best2, p)
                best[s][r]  = min(bo, p);
            }
        }
    }

    // 16-lane argmin reduce; col carried separately, selected by packed compare
    int colb[4][4];
    #pragma unroll
    for (int s = 0; s < 4; ++s)
        #pragma unroll
        for (int r = 0; r < 4; ++r) colb[s][r] = col;

    #pragma unroll
    for (int s = 0; s < 4; ++s) {
        #pragma unroll
        for (int off = 1; off < 16; off <<= 1) {
            #pragma unroll
            for (int r = 0; r < 4; ++r) {
                int ob  = __shfl_xor(best[s][r],  off);
                int ob2 = __shfl_xor(best2[s][r], off);
                int oc  = __shfl_xor(colb[s][r],  off);
                int bo  = best[s][r];
                colb[s][r]  = (ob < bo) ? oc : colb[s][r];  // ties keep self (flagged anyway)
                best[s][r]  = min(bo, ob);
                best2[s][r] = min(min(best2[s][r], ob2), max(bo, ob));
            }
        }
        #pragma unroll
        for (int r = 0; r < 4; ++r) {
            if (col == r) {                    // owner lane for this query row
                int   q  = qbase + 16*s + 4*g + r;
                int   pk = best[s][r];
                float a1 = __int_as_float(pk & 0xFFFFFFC0);          // acc-space
                float a2 = __int_as_float(best2[s][r] & 0xFFFFFFC0);
                int code = ((pk & 63) << 4) | colb[s][r];            // gt*16 + col
                idx_out[q] = (float)code;
                if (a2 - a1 < MARGIN_A) {      // ambiguous -> f64 rescue
                    int slot = atomicAdd(nflag, 1);
                    flag_list[slot] = q;
                }
            }
        }
    }
}

// ---------- K2: f64 rescore, coalesced eT + 4 independent dot chains (proven) ----------
__global__ __launch_bounds__(256) void k_rescue(const float* __restrict__ inp,
                                                const double* __restrict__ eT,
                                                const double* __restrict__ wB2D,
                                                const int* __restrict__ flag_list,
                                                const int* __restrict__ nflag,
                                                float* __restrict__ idx_out) {
    __shared__ double xh[DIM];
    __shared__ double Ash;
    __shared__ double sdw[4];
    __shared__ int    siw[4];
    const int tid = threadIdx.x;
    const int lane = tid & 63, wv = tid >> 6;
    const int n = *nflag;

    for (int j = blockIdx.x; j < n; j += gridDim.x) {   // uniform trip per block
        const int q = flag_list[j];
        if (tid < 64) {
            double xv = (double)inp[(size_t)q * DIM + tid];
            double s = xv * xv;
            #pragma unroll
            for (int off = 32; off; off >>= 1) s += __shfl_xor(s, off);
            double dn = fmax(sqrt(s), 1e-12);
            double h  = xv / dn;
            xh[tid] = h;
            double a = h * h;
            #pragma unroll
            for (int off = 32; off; off >>= 1) a += __shfl_xor(a, off);
            if (tid == 0) Ash = a;
        }
        __syncthreads();
        const double A = Ash;

        double dot0 = 0.0, dot1 = 0.0, dot2 = 0.0, dot3 = 0.0;
        #pragma unroll 8
        for (int i = 0; i < DIM; ++i) {
            double xi = xh[i];                           // LDS broadcast
            const double* row = eT + (size_t)i * KC + tid;
            dot0 += xi * row[0];
            dot1 += xi * row[256];
            dot2 += xi * row[512];
            dot3 += xi * row[768];
        }
        double bd = 1e300; int bi = 1 << 30;
        double d0 = (A + wB2D[tid      ]) - 2.0 * dot0;
        double d1 = (A + wB2D[tid + 256]) - 2.0 * dot1;
        double d2 = (A + wB2D[tid + 512]) - 2.0 * dot2;
        double d3 = (A + wB2D[tid + 768]) - 2.0 * dot3;
        if (d0 < bd) { bd = d0; bi = tid;       }        // ascending c: first-min
        if (d1 < bd) { bd = d1; bi = tid + 256; }
        if (d2 < bd) { bd = d2; bi = tid + 512; }
        if (d3 < bd) { bd = d3; bi = tid + 768; }
        #pragma unroll
        for (int off = 1; off < 64; off <<= 1) {         // 64-lane (d,i) min-reduce
            double od = __shfl_xor(bd, off);
            int    oi = __shfl_xor(bi, off);
            if (od < bd || (od == bd && oi < bi)) { bd = od; bi = oi; }
        }
        if (lane == 0) { sdw[wv] = bd; siw[wv] = bi; }
        __syncthreads();
        if (tid == 0) {
            double B = sdw[0]; int I = siw[0];
            #pragma unroll
            for (int i = 1; i < 4; ++i)
                if (sdw[i] < B || (sdw[i] == B && siw[i] < I)) { B = sdw[i]; I = siw[i]; }
            idx_out[q] = (float)I;                       // final
        }
        __syncthreads();
    }
}

// ---------- K3: gather + loss + hist, EXPLICIT 4-WAY ILP (r19-proven) ----------
__global__ __launch_bounds__(256) void k_gather_loss(const float* __restrict__ inp,
                                                     const float* __restrict__ emb,
                                                     const float* __restrict__ idx_out,
                                                     float* __restrict__ qout,
                                                     float* __restrict__ loss,
                                                     int* __restrict__ counts) {
    __shared__ int h[KC];
    const int tid = threadIdx.x;
    for (int i = tid; i < KC; i += 256) h[i] = 0;
    __syncthreads();

    const int gid = blockIdx.x * 256 + tid;            // 524288 threads x 4 e4 each

    int kk[4];
    #pragma unroll
    for (int it = 0; it < 4; ++it)
        kk[it] = ((int)idx_out[(gid + it * 524288) >> 4]) & (KC - 1);

    float4 qv[4], fv[4];
    #pragma unroll
    for (int it = 0; it < 4; ++it) {
        int e4 = gid + it * 524288;
        qv[it] = reinterpret_cast<const float4*>(emb + (size_t)kk[it] * DIM)[e4 & 15];
        fv[it] = reinterpret_cast<const float4*>(inp)[e4];
    }

    float lsum = 0.f;
    #pragma unroll
    for (int it = 0; it < 4; ++it) {
        int e4 = gid + it * 524288;
        float ux = qv[it].x - fv[it].x, uy = qv[it].y - fv[it].y;
        float uz = qv[it].z - fv[it].z, uw = qv[it].w - fv[it].w;
        lsum += ux*ux + uy*uy + uz*uz + uw*uw;
        reinterpret_cast<float4*>(qout)[e4] = qv[it];
        if ((e4 & 15) == 0) atomicAdd(&h[kk[it]], 1);  // count each query once
    }
    __syncthreads();                                   // hist adds done
    for (int i = tid; i < KC; i += 256) {
        int v = h[i];
        if (v) atomicAdd(&counts[i], v);
    }
    #pragma unroll
    for (int off = 32; off; off >>= 1) lsum += __shfl_xor(lsum, off);
    __shared__ float wsum[4];
    int wid = tid >> 6, lane = tid & 63;
    if (lane == 0) wsum[wid] = lsum;
    __syncthreads();
    if (tid == 0)
        atomicAdd(loss, (wsum[0] + wsum[1]) + (wsum[2] + wsum[3]));
}

// ---------- K4: perplexity / usage / vq_loss ----------
__global__ __launch_bounds__(1024) void k_stats2(const int* __restrict__ counts,
                                                 float* __restrict__ out3) {
    int t = threadIdx.x;
    int c = counts[t];
    float p    = (float)c * (1.0f / (float)NQ);
    float ent  = p * logf(p + 1e-10f);
    float used = (c > 0) ? 1.0f : 0.0f;
    #pragma unroll
    for (int off = 32; off; off >>= 1) {
        ent  += __shfl_xor(ent, off);
        used += __shfl_xor(used, off);
    }
    __shared__ float se[16], su[16];
    int w = t >> 6, l = t & 63;
    if (l == 0) { se[w] = ent; su[w] = used; }
    __syncthreads();
    if (t == 0) {
        float E = 0.f, U = 0.f;
        #pragma unroll
        for (int i = 0; i < 16; ++i) { E += se[i]; U += su[i]; }
        float L = out3[0];                             // loss accumulated here
        out3[0] = L * 1.25f / 8388608.0f;              // vq_loss (q + 0.25*e)
        out3[1] = expf(-E);                            // perplexity
        out3[2] = U * (1.0f / 1024.0f);                // codebook_usage
    }
}

// ---------- launch (5 kernels) ----------
// d_out (f32, 8519683): [0,8388608) quantized | [8388608,8519680) idx | 3 scalars
// Scratch in the quantized region (consumed by k_rescue, overwritten by gather):
//   flag_list @ float 0 (<=512 KB) | eT f64[64][1024] @ float 1048576 (512 KB)
// d_ws: counts[1024]@0 | wB u16[131072]@4096 | wB2D f64[1024]@266240 | nflag@274432
extern "C" void kernel_launch(void* const* d_in, const int* in_sizes, int n_in,
                              void* d_out, int out_size, void* d_ws, size_t ws_size,
                              hipStream_t stream) {
    const float* inp = (const float*)d_in[0];   // [32,4096,64] f32
    const float* emb = (const float*)d_in[1];   // [1024,64] f32

    float*  qout      = (float*)d_out;
    int*    flag_list = (int*)d_out;                        // quantized region, part 1
    double* eT        = (double*)((float*)d_out + 1048576); // quantized region, part 2
    float*  idx_out   = (float*)d_out + 8388608;
    float*  out3      = (float*)d_out + 8519680;

    int*            counts = (int*)d_ws;
    unsigned short* wB     = (unsigned short*)((char*)d_ws + 4096);
    double*         wB2D   = (double*)((char*)d_ws + 266240);
    int*            nflag  = (int*)((char*)d_ws + 274432);

    hipLaunchKernelGGL(k_prep,        dim3(1024), dim3(64),   0, stream,
                       emb, wB, eT, wB2D, counts, nflag, out3);
    hipLaunchKernelGGL(k_assign,      dim3(512),  dim3(256),  0, stream,
                       inp, wB, idx_out, flag_list, nflag);
    hipLaunchKernelGGL(k_rescue,      dim3(RGRID), dim3(256), 0, stream,
                       inp, eT, wB2D, flag_list, nflag, idx_out);
    hipLaunchKernelGGL(k_gather_loss, dim3(2048), dim3(256),  0, stream,
                       inp, emb, idx_out, qout, out3, counts);
    hipLaunchKernelGGL(k_stats2,      dim3(1),    dim3(1024), 0, stream, counts, out3);
}